// Round 6
// baseline (622.658 us; speedup 1.0000x reference)
//
#include <hip/hip_runtime.h>

#define N_TILE 50000
#define N_RR   50000
#define D      128
#define E_TT   800000
#define E_RT   400000
#define E_TR   400000
#define N_G    16
#define NB     ((N_TILE + 1023) / 1024)   // scan blocks per array (=49)
#define E_ALL  (E_TT + E_RT + E_TR)
#define BKT    8192                        // histogram bucket (bins per block), 32KB LDS
#define NBKT   ((N_TILE + BKT - 1) / BKT)  // =7
#define NCHK   16                          // edge chunks (all E divisible by 16)

static_assert(NB <= 64, "scan2 uses one wave per array");
static_assert(N_TILE == N_RR, "shared bucket geometry assumes equal node counts");
static_assert((BKT & (BKT - 1)) == 0, "bucket must be pow2");

// ---------------- bucketed LDS histogram: NO global atomics ----------------
// sides: 0=tt_dst 1=rt_dst 2=tr_dst 3=tt_src 4=rt_src 5=tr_src
// partial[s][c][bin] = count of value `bin` within edge-chunk c of side s.
__global__ __launch_bounds__(256) void k_hist(
    const int* __restrict__ tt_src, const int* __restrict__ tt_dst,
    const int* __restrict__ rt_src, const int* __restrict__ rt_dst,
    const int* __restrict__ tr_src, const int* __restrict__ tr_dst,
    int* __restrict__ partial) {
  __shared__ int h[BKT];
  int bid = blockIdx.x;
  int s = bid / (NBKT * NCHK);
  int rem = bid % (NBKT * NCHK);
  int b = rem / NCHK;
  int c = rem % NCHK;
  const int* arr; int E;
  switch (s) {
    case 0: arr = tt_dst; E = E_TT; break;
    case 1: arr = rt_dst; E = E_RT; break;
    case 2: arr = tr_dst; E = E_TR; break;
    case 3: arr = tt_src; E = E_TT; break;
    case 4: arr = rt_src; E = E_RT; break;
    default: arr = tr_src; E = E_TR; break;
  }
  for (int j = threadIdx.x; j < BKT; j += 256) h[j] = 0;
  __syncthreads();
  int ec = E / NCHK;
  int lo = c * ec, hi = lo + ec;
  int base = b * BKT;
  for (int i = lo + threadIdx.x; i < hi; i += 256) {
    unsigned int off = (unsigned int)(arr[i] - base);
    if (off < BKT) atomicAdd(&h[off], 1);
  }
  __syncthreads();
  int* dst = partial + (size_t)(s * NCHK + c) * N_TILE;
  for (int j = threadIdx.x; j < BKT; j += 256) {
    int bin = base + j;
    if (bin < N_TILE) dst[bin] = h[j];
  }
}

// ---------------- reduce partials ----------------
// dst sides (s<3): exclusive chunk-prefix written back in place (fill's chunk base)
//                  + total -> in-degree array.
// src sides (s>=3): total -> osc = rsqrt(max(od,1)) directly.
__global__ __launch_bounds__(256) void k_hreduce(
    int* __restrict__ partial,
    int* __restrict__ id_tt, int* __restrict__ id_rt, int* __restrict__ id_tr,
    float* __restrict__ os_tt, float* __restrict__ os_rt, float* __restrict__ os_tr) {
  int t = blockIdx.x * 256 + threadIdx.x;
  if (t >= 6 * N_TILE) return;
  int s = t / N_TILE;
  int i = t - s * N_TILE;
  int* p = partial + (size_t)s * NCHK * N_TILE + i;
  int run = 0;
  if (s < 3) {
#pragma unroll
    for (int c = 0; c < NCHK; ++c) {
      int v = p[(size_t)c * N_TILE];
      p[(size_t)c * N_TILE] = run;
      run += v;
    }
    if (s == 0) id_tt[i] = run;
    else if (s == 1) id_rt[i] = run;
    else id_tr[i] = run;
  } else {
#pragma unroll
    for (int c = 0; c < NCHK; ++c) run += p[(size_t)c * N_TILE];
    float v = rsqrtf((float)max(run, 1));
    if (s == 3) os_tt[i] = v;
    else if (s == 4) os_rt[i] = v;
    else os_tr[i] = v;
  }
}

// ---------------- scan stage 1: per-block exclusive scan (1024 elems/block) ----------------
__global__ __launch_bounds__(1024) void k_scan1(const int* __restrict__ d0,
                                                const int* __restrict__ d1,
                                                const int* __restrict__ d2,
                                                int* __restrict__ p0,
                                                int* __restrict__ p1,
                                                int* __restrict__ p2,
                                                int* __restrict__ bsum) {
  int arr = blockIdx.x / NB;
  int blk = blockIdx.x % NB;
  const int* deg = arr == 0 ? d0 : (arr == 1 ? d1 : d2);
  int* part = arr == 0 ? p0 : (arr == 1 ? p1 : p2);
  __shared__ int ts[1024];
  int tid = threadIdx.x;
  int i = blk * 1024 + tid;
  int v = (i < N_TILE) ? deg[i] : 0;
  ts[tid] = v;
  __syncthreads();
  for (int d = 1; d < 1024; d <<= 1) {
    int t = (tid >= d) ? ts[tid - d] : 0;
    __syncthreads();
    ts[tid] += t;
    __syncthreads();
  }
  if (i < N_TILE) part[i] = ts[tid] - v;   // exclusive within block
  if (tid == 1023) bsum[arr * NB + blk] = ts[1023];
}

// ---------------- scan stage 2: scan the block sums (1 wave / array) ----------------
__global__ __launch_bounds__(256) void k_scan2(const int* __restrict__ bsum,
                                               int* __restrict__ bs) {
  int wv = threadIdx.x >> 6;
  int lane = threadIdx.x & 63;
  if (wv >= 3) return;
  int v = (lane < NB) ? bsum[wv * NB + lane] : 0;
  int orig = v;
#pragma unroll
  for (int o = 1; o < 64; o <<= 1) {
    int t = __shfl_up(v, o);
    if (lane >= o) v += t;
  }
  if (lane < NB) bs[wv * (NB + 1) + lane] = v - orig;   // exclusive
  if (lane == NB - 1) bs[wv * (NB + 1) + NB] = v;       // total
}

// ---------------- finalize: rp = part + block offset; in-degree -> isc ----------------
__global__ void k_finalize(const int* __restrict__ pp_tt, const int* __restrict__ pp_rt,
                           const int* __restrict__ pp_tr, const int* __restrict__ bs,
                           int* __restrict__ rp_tt, int* __restrict__ rp_rt,
                           int* __restrict__ rp_tr,
                           const int* __restrict__ id_tt, const int* __restrict__ id_rt,
                           const int* __restrict__ id_tr,
                           float* __restrict__ is_tt, float* __restrict__ is_rt,
                           float* __restrict__ is_tr) {
  int i = blockIdx.x * blockDim.x + threadIdx.x;
  if (i >= N_TILE) return;
  int b = i >> 10;
  rp_tt[i] = pp_tt[i] + bs[0 * (NB + 1) + b];
  rp_rt[i] = pp_rt[i] + bs[1 * (NB + 1) + b];
  rp_tr[i] = pp_tr[i] + bs[2 * (NB + 1) + b];
  if (i == 0) {
    rp_tt[N_TILE] = bs[0 * (NB + 1) + NB];
    rp_rt[N_TILE] = bs[1 * (NB + 1) + NB];
    rp_tr[N_RR] = bs[2 * (NB + 1) + NB];
  }
  is_tt[i] = rsqrtf((float)max(id_tt[i], 1));
  is_rt[i] = rsqrtf((float)max(id_rt[i], 1));
  is_tr[i] = rsqrtf((float)max(id_tr[i], 1));
}

// ---------------- CSR fill: LDS cursors only (no global atomics) ----------------
// Block (relation s, bucket b, chunk c): cursor[bin] = rp[bin] + chunkbase[c][bin],
// then slots its chunk's edges with LDS atomicAdd; writes (src, osc[src]) pairs.
__global__ __launch_bounds__(256) void k_fill(
    const int* __restrict__ tt_src, const int* __restrict__ tt_dst,
    const int* __restrict__ rt_src, const int* __restrict__ rt_dst,
    const int* __restrict__ tr_src, const int* __restrict__ tr_dst,
    const int* __restrict__ rp_tt, const int* __restrict__ rp_rt,
    const int* __restrict__ rp_tr,
    const float* __restrict__ os_tt, const float* __restrict__ os_rt,
    const float* __restrict__ os_tr,
    const int* __restrict__ partial,
    int2* __restrict__ pr_tt, int2* __restrict__ pr_rt, int2* __restrict__ pr_tr) {
  __shared__ int cur[BKT];
  int bid = blockIdx.x;
  int s = bid / (NBKT * NCHK);
  int rem = bid % (NBKT * NCHK);
  int b = rem / NCHK;
  int c = rem % NCHK;
  const int* srcA; const int* dstA; const int* rp; const float* os; int2* pr; int E;
  if (s == 0) { srcA = tt_src; dstA = tt_dst; rp = rp_tt; os = os_tt; pr = pr_tt; E = E_TT; }
  else if (s == 1) { srcA = rt_src; dstA = rt_dst; rp = rp_rt; os = os_rt; pr = pr_rt; E = E_RT; }
  else { srcA = tr_src; dstA = tr_dst; rp = rp_tr; os = os_tr; pr = pr_tr; E = E_TR; }
  int base = b * BKT;
  const int* cb = partial + (size_t)(s * NCHK + c) * N_TILE;
  for (int j = threadIdx.x; j < BKT; j += 256) {
    int bin = base + j;
    if (bin < N_TILE) cur[j] = rp[bin] + cb[bin];
  }
  __syncthreads();
  int ec = E / NCHK;
  int lo = c * ec, hi = lo + ec;
  for (int i = lo + threadIdx.x; i < hi; i += 256) {
    int d = dstA[i];
    unsigned int off = (unsigned int)(d - base);
    if (off < BKT) {
      int slot = atomicAdd(&cur[off], 1);
      int sv = srcA[i];
      int2 v;
      v.x = sv;
      v.y = __float_as_int(os[sv]);
      pr[slot] = v;
    }
  }
}

// ---------------- fused aggregation: up to 3 relations, one wave per dst ----------------
// out[d] = isc[d] * sum_e w_e * x[src_e];  pairs pr[e] = (src_e, w_e)
// Half-wave layout: lanes 0-31 and 32-63 each load a full 512B row as float4
// -> one load instruction covers TWO edges. 4 rows in flight per half-wave.
__global__ __launch_bounds__(256) void k_agg3(
    const float* __restrict__ x0, const int* __restrict__ rp0, const int2* __restrict__ pr0,
    const float* __restrict__ isc0, float* __restrict__ out0, int n0,
    const float* __restrict__ x1, const int* __restrict__ rp1, const int2* __restrict__ pr1,
    const float* __restrict__ isc1, float* __restrict__ out1, int n1,
    const float* __restrict__ x2, const int* __restrict__ rp2, const int2* __restrict__ pr2,
    const float* __restrict__ isc2, float* __restrict__ out2, int n2) {
  int gw = (blockIdx.x * blockDim.x + threadIdx.x) >> 6;
  int lane = threadIdx.x & 63;
  int half = lane >> 5;      // which edge of the pair
  int l5 = lane & 31;        // float4 slot within the 128-float row
  const float* x; const int* rp; const int2* pr; const float* isc; float* out; int wid;
  if (gw < n0) { x = x0; rp = rp0; pr = pr0; isc = isc0; out = out0; wid = gw; }
  else if (gw < n0 + n1) { x = x1; rp = rp1; pr = pr1; isc = isc1; out = out1; wid = gw - n0; }
  else if (gw < n0 + n1 + n2) { x = x2; rp = rp2; pr = pr2; isc = isc2; out = out2; wid = gw - n0 - n1; }
  else return;
  int beg = rp[wid], end = rp[wid + 1];
  float4 a0 = make_float4(0.f, 0.f, 0.f, 0.f);
  float4 a1 = a0, a2 = a0, a3 = a0;
  const float4* xb = (const float4*)x + l5;
  for (int e = beg; e < end; e += 8) {
    int2 p0, p1, p2, p3;
    float w0, w1, w2, w3;
    {
      int i0 = e + 0 + half, i1 = e + 2 + half, i2 = e + 4 + half, i3 = e + 6 + half;
      int lim = end - 1;
      p0 = pr[min(i0, lim)];
      p1 = pr[min(i1, lim)];
      p2 = pr[min(i2, lim)];
      p3 = pr[min(i3, lim)];
      w0 = (i0 < end) ? __int_as_float(p0.y) : 0.f;
      w1 = (i1 < end) ? __int_as_float(p1.y) : 0.f;
      w2 = (i2 < end) ? __int_as_float(p2.y) : 0.f;
      w3 = (i3 < end) ? __int_as_float(p3.y) : 0.f;
    }
    float4 v0 = xb[(size_t)p0.x * 32];
    float4 v1 = xb[(size_t)p1.x * 32];
    float4 v2 = xb[(size_t)p2.x * 32];
    float4 v3 = xb[(size_t)p3.x * 32];
    a0.x = fmaf(v0.x, w0, a0.x); a0.y = fmaf(v0.y, w0, a0.y);
    a0.z = fmaf(v0.z, w0, a0.z); a0.w = fmaf(v0.w, w0, a0.w);
    a1.x = fmaf(v1.x, w1, a1.x); a1.y = fmaf(v1.y, w1, a1.y);
    a1.z = fmaf(v1.z, w1, a1.z); a1.w = fmaf(v1.w, w1, a1.w);
    a2.x = fmaf(v2.x, w2, a2.x); a2.y = fmaf(v2.y, w2, a2.y);
    a2.z = fmaf(v2.z, w2, a2.z); a2.w = fmaf(v2.w, w2, a2.w);
    a3.x = fmaf(v3.x, w3, a3.x); a3.y = fmaf(v3.y, w3, a3.y);
    a3.z = fmaf(v3.z, w3, a3.z); a3.w = fmaf(v3.w, w3, a3.w);
  }
  float4 s;
  s.x = (a0.x + a1.x) + (a2.x + a3.x);
  s.y = (a0.y + a1.y) + (a2.y + a3.y);
  s.z = (a0.z + a1.z) + (a2.z + a3.z);
  s.w = (a0.w + a1.w) + (a2.w + a3.w);
  // combine the two half-wave edge sets
  s.x += __shfl_xor(s.x, 32);
  s.y += __shfl_xor(s.y, 32);
  s.z += __shfl_xor(s.z, 32);
  s.w += __shfl_xor(s.w, 32);
  if (half == 0) {
    float iv = isc[wid];
    float4 r;
    r.x = s.x * iv; r.y = s.y * iv; r.z = s.z * iv; r.w = s.w * iv;
    ((float4*)(out + (size_t)wid * D))[l5] = r;
  }
}

// ---------------- fused GEMM(+GEMM) + bias + relu ----------------
// out[r][c] = relu( A[r,:]@W1[:,c] (+ B[r,:]@W2[:,c]) + b1[c] (+ b2[c]) )
#define GBM 64
#define GKC 32

template<bool TWO>
__global__ __launch_bounds__(256) void k_gemm(const float* __restrict__ A,
                                              const float* __restrict__ B,
                                              const float* __restrict__ W1,
                                              const float* __restrict__ W2,
                                              const float* __restrict__ b1,
                                              const float* __restrict__ b2,
                                              float* __restrict__ out, int nrows) {
  __shared__ float As[GBM][GKC + 1];
  __shared__ float Ws[GKC][132];
  int tid = threadIdx.x;
  int tx = tid & 15, ty = tid >> 4;
  int r0 = blockIdx.x * GBM;
  float acc[4][8];
#pragma unroll
  for (int i = 0; i < 4; ++i)
#pragma unroll
    for (int j = 0; j < 8; ++j) acc[i][j] = 0.f;

  const int nrel = TWO ? 2 : 1;
  for (int rel = 0; rel < nrel; ++rel) {
    const float* __restrict__ Xp = (rel == 0) ? A : B;
    const float* __restrict__ Wp = (rel == 0) ? W1 : W2;
    for (int k0 = 0; k0 < D; k0 += GKC) {
      {
        int lr = tid >> 3;
        int lk = (tid & 7) * 4;
#pragma unroll
        for (int h = 0; h < 2; ++h) {
          int rr = lr + h * 32;
          int gr = r0 + rr;
          float4 v = make_float4(0.f, 0.f, 0.f, 0.f);
          if (gr < nrows) v = *(const float4*)(Xp + (size_t)gr * D + k0 + lk);
          As[rr][lk] = v.x; As[rr][lk + 1] = v.y; As[rr][lk + 2] = v.z; As[rr][lk + 3] = v.w;
        }
        int wk = tid >> 5;
        int wc = (tid & 31) * 4;
#pragma unroll
        for (int h = 0; h < 4; ++h) {
          int kk = wk + h * 8;
          float4 v = *(const float4*)(Wp + (size_t)(k0 + kk) * D + wc);
          *(float4*)&Ws[kk][wc] = v;
        }
      }
      __syncthreads();
#pragma unroll 8
      for (int k = 0; k < GKC; ++k) {
        float a0 = As[ty * 4 + 0][k];
        float a1 = As[ty * 4 + 1][k];
        float a2 = As[ty * 4 + 2][k];
        float a3 = As[ty * 4 + 3][k];
        float4 bA = *(const float4*)&Ws[k][tx * 4];
        float4 bB = *(const float4*)&Ws[k][64 + tx * 4];
        acc[0][0] = fmaf(a0, bA.x, acc[0][0]); acc[0][1] = fmaf(a0, bA.y, acc[0][1]);
        acc[0][2] = fmaf(a0, bA.z, acc[0][2]); acc[0][3] = fmaf(a0, bA.w, acc[0][3]);
        acc[0][4] = fmaf(a0, bB.x, acc[0][4]); acc[0][5] = fmaf(a0, bB.y, acc[0][5]);
        acc[0][6] = fmaf(a0, bB.z, acc[0][6]); acc[0][7] = fmaf(a0, bB.w, acc[0][7]);
        acc[1][0] = fmaf(a1, bA.x, acc[1][0]); acc[1][1] = fmaf(a1, bA.y, acc[1][1]);
        acc[1][2] = fmaf(a1, bA.z, acc[1][2]); acc[1][3] = fmaf(a1, bA.w, acc[1][3]);
        acc[1][4] = fmaf(a1, bB.x, acc[1][4]); acc[1][5] = fmaf(a1, bB.y, acc[1][5]);
        acc[1][6] = fmaf(a1, bB.z, acc[1][6]); acc[1][7] = fmaf(a1, bB.w, acc[1][7]);
        acc[2][0] = fmaf(a2, bA.x, acc[2][0]); acc[2][1] = fmaf(a2, bA.y, acc[2][1]);
        acc[2][2] = fmaf(a2, bA.z, acc[2][2]); acc[2][3] = fmaf(a2, bA.w, acc[2][3]);
        acc[2][4] = fmaf(a2, bB.x, acc[2][4]); acc[2][5] = fmaf(a2, bB.y, acc[2][5]);
        acc[2][6] = fmaf(a2, bB.z, acc[2][6]); acc[2][7] = fmaf(a2, bB.w, acc[2][7]);
        acc[3][0] = fmaf(a3, bA.x, acc[3][0]); acc[3][1] = fmaf(a3, bA.y, acc[3][1]);
        acc[3][2] = fmaf(a3, bA.z, acc[3][2]); acc[3][3] = fmaf(a3, bA.w, acc[3][3]);
        acc[3][4] = fmaf(a3, bB.x, acc[3][4]); acc[3][5] = fmaf(a3, bB.y, acc[3][5]);
        acc[3][6] = fmaf(a3, bB.z, acc[3][6]); acc[3][7] = fmaf(a3, bB.w, acc[3][7]);
      }
      __syncthreads();
    }
  }

  float4 c0 = *(const float4*)&b1[tx * 4];
  float4 c1 = *(const float4*)&b1[64 + tx * 4];
  if constexpr (TWO) {
    float4 d0 = *(const float4*)&b2[tx * 4];
    float4 d1 = *(const float4*)&b2[64 + tx * 4];
    c0.x += d0.x; c0.y += d0.y; c0.z += d0.z; c0.w += d0.w;
    c1.x += d1.x; c1.y += d1.y; c1.z += d1.z; c1.w += d1.w;
  }
#pragma unroll
  for (int i = 0; i < 4; ++i) {
    int gr = r0 + ty * 4 + i;
    if (gr < nrows) {
      float4 o0, o1;
      o0.x = fmaxf(acc[i][0] + c0.x, 0.f);
      o0.y = fmaxf(acc[i][1] + c0.y, 0.f);
      o0.z = fmaxf(acc[i][2] + c0.z, 0.f);
      o0.w = fmaxf(acc[i][3] + c0.w, 0.f);
      o1.x = fmaxf(acc[i][4] + c1.x, 0.f);
      o1.y = fmaxf(acc[i][5] + c1.y, 0.f);
      o1.z = fmaxf(acc[i][6] + c1.z, 0.f);
      o1.w = fmaxf(acc[i][7] + c1.w, 0.f);
      *(float4*)(out + (size_t)gr * D + tx * 4) = o0;
      *(float4*)(out + (size_t)gr * D + 64 + tx * 4) = o1;
    }
  }
}

// ---------------- per-graph mean pooling (sorted gid -> segment partials) ----------------
#define PCHUNK 256
__global__ __launch_bounds__(128) void k_pool(const float* __restrict__ H,
                                              const int* __restrict__ gid,
                                              float* __restrict__ sums,
                                              float* __restrict__ cnt, int n) {
  int col = threadIdx.x;
  int start = blockIdx.x * PCHUNK;
  if (start >= n) return;
  int end = min(start + PCHUNK, n);
  float acc = 0.f;
  int cur = gid[start];
  int seglen = 0;
  for (int r = start; r < end; ++r) {
    int g = gid[r];
    if (g != cur) {
      atomicAdd(&sums[cur * D + col], acc);
      if (col == 0) atomicAdd(&cnt[cur], (float)seglen);
      acc = 0.f; seglen = 0; cur = g;
    }
    acc += H[(size_t)r * D + col];
    seglen++;
  }
  atomicAdd(&sums[cur * D + col], acc);
  if (col == 0) atomicAdd(&cnt[cur], (float)seglen);
}

// ---------------- final MLP on [16,128] ----------------
__global__ __launch_bounds__(256) void k_final(const float* __restrict__ sums,
                                               const float* __restrict__ cnt,
                                               const float* __restrict__ Wm1,
                                               const float* __restrict__ bm1,
                                               const float* __restrict__ Wm2,
                                               const float* __restrict__ bm2,
                                               float* __restrict__ out) {
  __shared__ float hg[16][128];
  __shared__ float t1[16][128];
  int tid = threadIdx.x;
  for (int i = tid; i < 16 * 128; i += 256) {
    int g = i >> 7, c = i & 127;
    hg[g][c] = sums[i] / fmaxf(cnt[g], 1.f);
  }
  __syncthreads();
  for (int i = tid; i < 16 * 128; i += 256) {
    int g = i >> 7, c = i & 127;
    float a = bm1[c];
    for (int k = 0; k < 128; ++k) a = fmaf(hg[g][k], Wm1[k * 128 + c], a);
    t1[g][c] = fmaxf(a, 0.f);
  }
  __syncthreads();
  int g = tid >> 4, l = tid & 15;
  float p = 0.f;
  for (int c = l; c < 128; c += 16) p = fmaf(t1[g][c], Wm2[c], p);
#pragma unroll
  for (int o = 8; o; o >>= 1) p += __shfl_down(p, o, 16);
  if (l == 0) out[g] = p + bm2[0];
}

extern "C" void kernel_launch(void* const* d_in, const int* in_sizes, int n_in,
                              void* d_out, int out_size, void* d_ws, size_t ws_size,
                              hipStream_t stream) {
  const float* x_tile = (const float*)d_in[0];
  const float* x_rr   = (const float*)d_in[1];
  const int* tt_src = (const int*)d_in[2];
  const int* tt_dst = (const int*)d_in[3];
  const int* rt_src = (const int*)d_in[4];
  const int* rt_dst = (const int*)d_in[5];
  const int* tr_src = (const int*)d_in[6];
  const int* tr_dst = (const int*)d_in[7];
  const int* tile_gid = (const int*)d_in[8];
  const float* W1_tt = (const float*)d_in[9];  const float* b1_tt = (const float*)d_in[10];
  const float* W1_rt = (const float*)d_in[11]; const float* b1_rt = (const float*)d_in[12];
  const float* W1_tr = (const float*)d_in[13]; const float* b1_tr = (const float*)d_in[14];
  const float* W2_tt = (const float*)d_in[15]; const float* b2_tt = (const float*)d_in[16];
  const float* W2_rt = (const float*)d_in[17]; const float* b2_rt = (const float*)d_in[18];
  const float* Wm1 = (const float*)d_in[21]; const float* bm1 = (const float*)d_in[22];
  const float* Wm2 = (const float*)d_in[23]; const float* bm2 = (const float*)d_in[24];

  char* ws = (char*)d_ws;
  size_t off = 0;
  auto alloc = [&](size_t elems) {
    void* p = ws + off;
    off += (elems * 4 + 255) & ~(size_t)255;
    return p;
  };
  // ---- zero region (memset each call) ----
  float* psum = (float*)alloc(N_G * D);
  float* pcnt = (float*)alloc(N_G);
  size_t zero_bytes = off;
  // ---- rest (all fully written before read) ----
  int* partial = (int*)alloc((size_t)6 * NCHK * N_TILE);
  int* ideg_tt = (int*)alloc(N_TILE);
  int* ideg_rt = (int*)alloc(N_TILE);
  int* ideg_tr = (int*)alloc(N_RR);
  int* pp_tt = (int*)alloc(N_TILE);
  int* pp_rt = (int*)alloc(N_TILE);
  int* pp_tr = (int*)alloc(N_RR);
  int* bsum = (int*)alloc(3 * NB);
  int* bs = (int*)alloc(3 * (NB + 1));
  int* rp_tt = (int*)alloc(N_TILE + 1);
  int* rp_rt = (int*)alloc(N_TILE + 1);
  int* rp_tr = (int*)alloc(N_RR + 1);
  int2* pr_tt = (int2*)alloc((size_t)E_TT * 2);
  int2* pr_rt = (int2*)alloc((size_t)E_RT * 2);
  int2* pr_tr = (int2*)alloc((size_t)E_TR * 2);
  float* osc_tt = (float*)alloc(N_TILE);
  float* osc_rt = (float*)alloc(N_RR);
  float* osc_tr = (float*)alloc(N_TILE);
  float* isc_tt = (float*)alloc(N_TILE);
  float* isc_rt = (float*)alloc(N_TILE);
  float* isc_tr = (float*)alloc(N_RR);
  float* Abuf = (float*)alloc((size_t)N_TILE * D);
  float* Bbuf = (float*)alloc((size_t)N_TILE * D);
  float* Htile = (float*)alloc((size_t)N_TILE * D);
  float* Hrr = (float*)alloc((size_t)N_RR * D);
  (void)ws_size; (void)in_sizes; (void)n_in; (void)out_size;

  hipMemsetAsync(d_ws, 0, zero_bytes, stream);

  // ---- CSR build: zero global atomics ----
  k_hist<<<6 * NBKT * NCHK, 256, 0, stream>>>(
      tt_src, tt_dst, rt_src, rt_dst, tr_src, tr_dst, partial);
  k_hreduce<<<(6 * N_TILE + 255) / 256, 256, 0, stream>>>(
      partial, ideg_tt, ideg_rt, ideg_tr, osc_tt, osc_rt, osc_tr);
  k_scan1<<<3 * NB, 1024, 0, stream>>>(ideg_tt, ideg_rt, ideg_tr, pp_tt, pp_rt, pp_tr, bsum);
  k_scan2<<<1, 256, 0, stream>>>(bsum, bs);
  k_finalize<<<(N_TILE + 255) / 256, 256, 0, stream>>>(
      pp_tt, pp_rt, pp_tr, bs, rp_tt, rp_rt, rp_tr,
      ideg_tt, ideg_rt, ideg_tr, isc_tt, isc_rt, isc_tr);
  k_fill<<<3 * NBKT * NCHK, 256, 0, stream>>>(
      tt_src, tt_dst, rt_src, rt_dst, tr_src, tr_dst,
      rp_tt, rp_rt, rp_tr, osc_tt, osc_rt, osc_tr,
      partial, pr_tt, pr_rt, pr_tr);

  const int gemmBlocks = (N_TILE + GBM - 1) / GBM;

  // ---- layer 1: all three aggs fused (tr output parked in Htile) ----
  {
    int totw = N_TILE + N_TILE + N_RR;
    k_agg3<<<(totw * 64 + 255) / 256, 256, 0, stream>>>(
        x_tile, rp_tt, pr_tt, isc_tt, Abuf, N_TILE,
        x_rr,  rp_rt, pr_rt, isc_rt, Bbuf, N_TILE,
        x_tile, rp_tr, pr_tr, isc_tr, Htile, N_RR);
  }
  // tr GEMM first (consumes Htile before it is overwritten)
  k_gemm<false><<<gemmBlocks, 256, 0, stream>>>(Htile, nullptr, W1_tr, nullptr, b1_tr, nullptr, Hrr, N_RR);
  k_gemm<true><<<gemmBlocks, 256, 0, stream>>>(Abuf, Bbuf, W1_tt, W1_rt, b1_tt, b1_rt, Htile, N_TILE);

  // ---- layer 2 (h2_rr never consumed -> tr relation skipped) ----
  {
    int totw = N_TILE + N_TILE;
    k_agg3<<<(totw * 64 + 255) / 256, 256, 0, stream>>>(
        Htile, rp_tt, pr_tt, isc_tt, Abuf, N_TILE,
        Hrr,   rp_rt, pr_rt, isc_rt, Bbuf, N_TILE,
        nullptr, nullptr, nullptr, nullptr, nullptr, 0);
  }
  k_gemm<true><<<gemmBlocks, 256, 0, stream>>>(Abuf, Bbuf, W2_tt, W2_rt, b2_tt, b2_rt, Htile, N_TILE);

  // ---- pooling + MLP head ----
  k_pool<<<(N_TILE + PCHUNK - 1) / PCHUNK, 128, 0, stream>>>(Htile, tile_gid, psum, pcnt, N_TILE);
  k_final<<<1, 256, 0, stream>>>(psum, pcnt, Wm1, bm1, Wm2, bm2, (float*)d_out);
}

// Round 7
// 533.203 us; speedup vs baseline: 1.1678x; 1.1678x over previous
//
#include <hip/hip_runtime.h>

#define N_TILE 50000
#define N_RR   50000
#define D      128
#define E_TT   800000
#define E_RT   400000
#define E_TR   400000
#define N_G    16
#define NB     ((N_TILE + 1023) / 1024)   // scan blocks per array (=49)
#define E_ALL  (E_TT + E_RT + E_TR)
#define BKT    8192                        // histogram bucket (bins per block), 32KB LDS
#define NBKT   ((N_TILE + BKT - 1) / BKT)  // =7
#define NCHK   25                          // edge chunks (all E divisible by 25)

static_assert(NB <= 64, "scan2 uses one wave per array");
static_assert(N_TILE == N_RR, "shared bucket geometry assumes equal node counts");
static_assert((BKT & (BKT - 1)) == 0, "bucket must be pow2");
static_assert(E_TT % NCHK == 0 && E_RT % NCHK == 0 && E_TR % NCHK == 0, "chunking");

// ---------------- bucketed LDS histogram + rank capture: NO global atomics ----
// sides: 0=tt_dst 1=rt_dst 2=tr_dst 3=tt_src 4=rt_src 5=tr_src
// partial[s][c][bin] = count of value `bin` within edge-chunk c of side s.
// For dst sides, rank[e] = atomic return = e's order within (bin, chunk).
__global__ __launch_bounds__(256) void k_hist(
    const int* __restrict__ tt_src, const int* __restrict__ tt_dst,
    const int* __restrict__ rt_src, const int* __restrict__ rt_dst,
    const int* __restrict__ tr_src, const int* __restrict__ tr_dst,
    int* __restrict__ partial, int* __restrict__ rank) {
  __shared__ int h[BKT];
  int bid = blockIdx.x;
  int s = bid / (NBKT * NCHK);
  int rem = bid % (NBKT * NCHK);
  int b = rem / NCHK;
  int c = rem % NCHK;
  const int* arr; int E; int roff = 0;
  switch (s) {
    case 0: arr = tt_dst; E = E_TT; roff = 0; break;
    case 1: arr = rt_dst; E = E_RT; roff = E_TT; break;
    case 2: arr = tr_dst; E = E_TR; roff = E_TT + E_RT; break;
    case 3: arr = tt_src; E = E_TT; break;
    case 4: arr = rt_src; E = E_RT; break;
    default: arr = tr_src; E = E_TR; break;
  }
  bool isdst = s < 3;
  for (int j = threadIdx.x; j < BKT; j += 256) h[j] = 0;
  __syncthreads();
  int ec = E / NCHK;
  int lo = c * ec, hi = lo + ec;
  int base = b * BKT;
  for (int i = lo + threadIdx.x; i < hi; i += 256) {
    unsigned int off = (unsigned int)(arr[i] - base);
    if (off < BKT) {
      int r = atomicAdd(&h[off], 1);
      if (isdst) rank[roff + i] = r;
    }
  }
  __syncthreads();
  int* dst = partial + (size_t)(s * NCHK + c) * N_TILE;
  for (int j = threadIdx.x; j < BKT; j += 256) {
    int bin = base + j;
    if (bin < N_TILE) dst[bin] = h[j];
  }
}

// ---------------- reduce partials ----------------
// dst sides (s<3): exclusive chunk-prefix written back in place (fill's chunk base)
//                  + total -> in-degree array.
// src sides (s>=3): total -> osc = rsqrt(max(od,1)) directly.
__global__ __launch_bounds__(256) void k_hreduce(
    int* __restrict__ partial,
    int* __restrict__ id_tt, int* __restrict__ id_rt, int* __restrict__ id_tr,
    float* __restrict__ os_tt, float* __restrict__ os_rt, float* __restrict__ os_tr) {
  int t = blockIdx.x * 256 + threadIdx.x;
  if (t >= 6 * N_TILE) return;
  int s = t / N_TILE;
  int i = t - s * N_TILE;
  int* p = partial + (size_t)s * NCHK * N_TILE + i;
  int run = 0;
  if (s < 3) {
#pragma unroll
    for (int c = 0; c < NCHK; ++c) {
      int v = p[(size_t)c * N_TILE];
      p[(size_t)c * N_TILE] = run;
      run += v;
    }
    if (s == 0) id_tt[i] = run;
    else if (s == 1) id_rt[i] = run;
    else id_tr[i] = run;
  } else {
#pragma unroll
    for (int c = 0; c < NCHK; ++c) run += p[(size_t)c * N_TILE];
    float v = rsqrtf((float)max(run, 1));
    if (s == 3) os_tt[i] = v;
    else if (s == 4) os_rt[i] = v;
    else os_tr[i] = v;
  }
}

// ---------------- scan stage 1: per-block exclusive scan (1024 elems/block) ----------------
__global__ __launch_bounds__(1024) void k_scan1(const int* __restrict__ d0,
                                                const int* __restrict__ d1,
                                                const int* __restrict__ d2,
                                                int* __restrict__ p0,
                                                int* __restrict__ p1,
                                                int* __restrict__ p2,
                                                int* __restrict__ bsum) {
  int arr = blockIdx.x / NB;
  int blk = blockIdx.x % NB;
  const int* deg = arr == 0 ? d0 : (arr == 1 ? d1 : d2);
  int* part = arr == 0 ? p0 : (arr == 1 ? p1 : p2);
  __shared__ int ts[1024];
  int tid = threadIdx.x;
  int i = blk * 1024 + tid;
  int v = (i < N_TILE) ? deg[i] : 0;
  ts[tid] = v;
  __syncthreads();
  for (int d = 1; d < 1024; d <<= 1) {
    int t = (tid >= d) ? ts[tid - d] : 0;
    __syncthreads();
    ts[tid] += t;
    __syncthreads();
  }
  if (i < N_TILE) part[i] = ts[tid] - v;   // exclusive within block
  if (tid == 1023) bsum[arr * NB + blk] = ts[1023];
}

// ---------------- scan stage 2: scan the block sums (1 wave / array) ----------------
__global__ __launch_bounds__(256) void k_scan2(const int* __restrict__ bsum,
                                               int* __restrict__ bs) {
  int wv = threadIdx.x >> 6;
  int lane = threadIdx.x & 63;
  if (wv >= 3) return;
  int v = (lane < NB) ? bsum[wv * NB + lane] : 0;
  int orig = v;
#pragma unroll
  for (int o = 1; o < 64; o <<= 1) {
    int t = __shfl_up(v, o);
    if (lane >= o) v += t;
  }
  if (lane < NB) bs[wv * (NB + 1) + lane] = v - orig;   // exclusive
  if (lane == NB - 1) bs[wv * (NB + 1) + NB] = v;       // total
}

// ---------------- finalize: rp = part + block offset; in-degree -> isc ----------------
__global__ void k_finalize(const int* __restrict__ pp_tt, const int* __restrict__ pp_rt,
                           const int* __restrict__ pp_tr, const int* __restrict__ bs,
                           int* __restrict__ rp_tt, int* __restrict__ rp_rt,
                           int* __restrict__ rp_tr,
                           const int* __restrict__ id_tt, const int* __restrict__ id_rt,
                           const int* __restrict__ id_tr,
                           float* __restrict__ is_tt, float* __restrict__ is_rt,
                           float* __restrict__ is_tr) {
  int i = blockIdx.x * blockDim.x + threadIdx.x;
  if (i >= N_TILE) return;
  int b = i >> 10;
  rp_tt[i] = pp_tt[i] + bs[0 * (NB + 1) + b];
  rp_rt[i] = pp_rt[i] + bs[1 * (NB + 1) + b];
  rp_tr[i] = pp_tr[i] + bs[2 * (NB + 1) + b];
  if (i == 0) {
    rp_tt[N_TILE] = bs[0 * (NB + 1) + NB];
    rp_rt[N_TILE] = bs[1 * (NB + 1) + NB];
    rp_tr[N_RR] = bs[2 * (NB + 1) + NB];
  }
  is_tt[i] = rsqrtf((float)max(id_tt[i], 1));
  is_rt[i] = rsqrtf((float)max(id_rt[i], 1));
  is_tr[i] = rsqrtf((float)max(id_tr[i], 1));
}

// ---------------- CSR fill: one thread per edge, atomic-free ----------------
// slot = rp[dst] + chunkbase[c][dst] + rank[e]; writes (src, osc[src]) pairs.
__global__ __launch_bounds__(256) void k_fill(
    const int* __restrict__ tt_src, const int* __restrict__ tt_dst,
    const int* __restrict__ rt_src, const int* __restrict__ rt_dst,
    const int* __restrict__ tr_src, const int* __restrict__ tr_dst,
    const int* __restrict__ rp_tt, const int* __restrict__ rp_rt,
    const int* __restrict__ rp_tr,
    const float* __restrict__ os_tt, const float* __restrict__ os_rt,
    const float* __restrict__ os_tr,
    const int* __restrict__ partial, const int* __restrict__ rank,
    int2* __restrict__ pr_tt, int2* __restrict__ pr_rt, int2* __restrict__ pr_tr) {
  int i = blockIdx.x * 256 + threadIdx.x;
  if (i >= E_ALL) return;
  const int* srcA; const int* dstA; const int* rp; const float* os; int2* pr;
  int j, s, ec;
  if (i < E_TT) {
    s = 0; j = i; ec = E_TT / NCHK;
    srcA = tt_src; dstA = tt_dst; rp = rp_tt; os = os_tt; pr = pr_tt;
  } else if (i < E_TT + E_RT) {
    s = 1; j = i - E_TT; ec = E_RT / NCHK;
    srcA = rt_src; dstA = rt_dst; rp = rp_rt; os = os_rt; pr = pr_rt;
  } else {
    s = 2; j = i - E_TT - E_RT; ec = E_TR / NCHK;
    srcA = tr_src; dstA = tr_dst; rp = rp_tr; os = os_tr; pr = pr_tr;
  }
  int d = dstA[j];
  int c = j / ec;
  int slot = rp[d] + partial[(size_t)(s * NCHK + c) * N_TILE + d] + rank[i];
  int sv = srcA[j];
  int2 v;
  v.x = sv;
  v.y = __float_as_int(os[sv]);
  pr[slot] = v;
}

// ---------------- fused aggregation: up to 3 relations, one wave per dst ----------------
// out[d] = isc[d] * sum_e w_e * x[src_e];  pairs pr[e] = (src_e, w_e)
// Half-wave layout: lanes 0-31 and 32-63 each load a full 512B row as float4
// -> one load instruction covers TWO edges. 4 rows in flight per half-wave.
__global__ __launch_bounds__(256) void k_agg3(
    const float* __restrict__ x0, const int* __restrict__ rp0, const int2* __restrict__ pr0,
    const float* __restrict__ isc0, float* __restrict__ out0, int n0,
    const float* __restrict__ x1, const int* __restrict__ rp1, const int2* __restrict__ pr1,
    const float* __restrict__ isc1, float* __restrict__ out1, int n1,
    const float* __restrict__ x2, const int* __restrict__ rp2, const int2* __restrict__ pr2,
    const float* __restrict__ isc2, float* __restrict__ out2, int n2) {
  int gw = (blockIdx.x * blockDim.x + threadIdx.x) >> 6;
  int lane = threadIdx.x & 63;
  int half = lane >> 5;      // which edge of the pair
  int l5 = lane & 31;        // float4 slot within the 128-float row
  const float* x; const int* rp; const int2* pr; const float* isc; float* out; int wid;
  if (gw < n0) { x = x0; rp = rp0; pr = pr0; isc = isc0; out = out0; wid = gw; }
  else if (gw < n0 + n1) { x = x1; rp = rp1; pr = pr1; isc = isc1; out = out1; wid = gw - n0; }
  else if (gw < n0 + n1 + n2) { x = x2; rp = rp2; pr = pr2; isc = isc2; out = out2; wid = gw - n0 - n1; }
  else return;
  int beg = rp[wid], end = rp[wid + 1];
  float4 a0 = make_float4(0.f, 0.f, 0.f, 0.f);
  float4 a1 = a0, a2 = a0, a3 = a0;
  const float4* xb = (const float4*)x + l5;
  for (int e = beg; e < end; e += 8) {
    int2 p0, p1, p2, p3;
    float w0, w1, w2, w3;
    {
      int i0 = e + 0 + half, i1 = e + 2 + half, i2 = e + 4 + half, i3 = e + 6 + half;
      int lim = end - 1;
      p0 = pr[min(i0, lim)];
      p1 = pr[min(i1, lim)];
      p2 = pr[min(i2, lim)];
      p3 = pr[min(i3, lim)];
      w0 = (i0 < end) ? __int_as_float(p0.y) : 0.f;
      w1 = (i1 < end) ? __int_as_float(p1.y) : 0.f;
      w2 = (i2 < end) ? __int_as_float(p2.y) : 0.f;
      w3 = (i3 < end) ? __int_as_float(p3.y) : 0.f;
    }
    float4 v0 = xb[(size_t)p0.x * 32];
    float4 v1 = xb[(size_t)p1.x * 32];
    float4 v2 = xb[(size_t)p2.x * 32];
    float4 v3 = xb[(size_t)p3.x * 32];
    a0.x = fmaf(v0.x, w0, a0.x); a0.y = fmaf(v0.y, w0, a0.y);
    a0.z = fmaf(v0.z, w0, a0.z); a0.w = fmaf(v0.w, w0, a0.w);
    a1.x = fmaf(v1.x, w1, a1.x); a1.y = fmaf(v1.y, w1, a1.y);
    a1.z = fmaf(v1.z, w1, a1.z); a1.w = fmaf(v1.w, w1, a1.w);
    a2.x = fmaf(v2.x, w2, a2.x); a2.y = fmaf(v2.y, w2, a2.y);
    a2.z = fmaf(v2.z, w2, a2.z); a2.w = fmaf(v2.w, w2, a2.w);
    a3.x = fmaf(v3.x, w3, a3.x); a3.y = fmaf(v3.y, w3, a3.y);
    a3.z = fmaf(v3.z, w3, a3.z); a3.w = fmaf(v3.w, w3, a3.w);
  }
  float4 s;
  s.x = (a0.x + a1.x) + (a2.x + a3.x);
  s.y = (a0.y + a1.y) + (a2.y + a3.y);
  s.z = (a0.z + a1.z) + (a2.z + a3.z);
  s.w = (a0.w + a1.w) + (a2.w + a3.w);
  // combine the two half-wave edge sets
  s.x += __shfl_xor(s.x, 32);
  s.y += __shfl_xor(s.y, 32);
  s.z += __shfl_xor(s.z, 32);
  s.w += __shfl_xor(s.w, 32);
  if (half == 0) {
    float iv = isc[wid];
    float4 r;
    r.x = s.x * iv; r.y = s.y * iv; r.z = s.z * iv; r.w = s.w * iv;
    ((float4*)(out + (size_t)wid * D))[l5] = r;
  }
}

// ---------------- fused GEMM(+GEMM) + bias + relu ----------------
// out[r][c] = relu( A[r,:]@W1[:,c] (+ B[r,:]@W2[:,c]) + b1[c] (+ b2[c]) )
#define GBM 64
#define GKC 32

template<bool TWO>
__global__ __launch_bounds__(256) void k_gemm(const float* __restrict__ A,
                                              const float* __restrict__ B,
                                              const float* __restrict__ W1,
                                              const float* __restrict__ W2,
                                              const float* __restrict__ b1,
                                              const float* __restrict__ b2,
                                              float* __restrict__ out, int nrows) {
  __shared__ float As[GBM][GKC + 1];
  __shared__ float Ws[GKC][132];
  int tid = threadIdx.x;
  int tx = tid & 15, ty = tid >> 4;
  int r0 = blockIdx.x * GBM;
  float acc[4][8];
#pragma unroll
  for (int i = 0; i < 4; ++i)
#pragma unroll
    for (int j = 0; j < 8; ++j) acc[i][j] = 0.f;

  const int nrel = TWO ? 2 : 1;
  for (int rel = 0; rel < nrel; ++rel) {
    const float* __restrict__ Xp = (rel == 0) ? A : B;
    const float* __restrict__ Wp = (rel == 0) ? W1 : W2;
    for (int k0 = 0; k0 < D; k0 += GKC) {
      {
        int lr = tid >> 3;
        int lk = (tid & 7) * 4;
#pragma unroll
        for (int h = 0; h < 2; ++h) {
          int rr = lr + h * 32;
          int gr = r0 + rr;
          float4 v = make_float4(0.f, 0.f, 0.f, 0.f);
          if (gr < nrows) v = *(const float4*)(Xp + (size_t)gr * D + k0 + lk);
          As[rr][lk] = v.x; As[rr][lk + 1] = v.y; As[rr][lk + 2] = v.z; As[rr][lk + 3] = v.w;
        }
        int wk = tid >> 5;
        int wc = (tid & 31) * 4;
#pragma unroll
        for (int h = 0; h < 4; ++h) {
          int kk = wk + h * 8;
          float4 v = *(const float4*)(Wp + (size_t)(k0 + kk) * D + wc);
          *(float4*)&Ws[kk][wc] = v;
        }
      }
      __syncthreads();
#pragma unroll 8
      for (int k = 0; k < GKC; ++k) {
        float a0 = As[ty * 4 + 0][k];
        float a1 = As[ty * 4 + 1][k];
        float a2 = As[ty * 4 + 2][k];
        float a3 = As[ty * 4 + 3][k];
        float4 bA = *(const float4*)&Ws[k][tx * 4];
        float4 bB = *(const float4*)&Ws[k][64 + tx * 4];
        acc[0][0] = fmaf(a0, bA.x, acc[0][0]); acc[0][1] = fmaf(a0, bA.y, acc[0][1]);
        acc[0][2] = fmaf(a0, bA.z, acc[0][2]); acc[0][3] = fmaf(a0, bA.w, acc[0][3]);
        acc[0][4] = fmaf(a0, bB.x, acc[0][4]); acc[0][5] = fmaf(a0, bB.y, acc[0][5]);
        acc[0][6] = fmaf(a0, bB.z, acc[0][6]); acc[0][7] = fmaf(a0, bB.w, acc[0][7]);
        acc[1][0] = fmaf(a1, bA.x, acc[1][0]); acc[1][1] = fmaf(a1, bA.y, acc[1][1]);
        acc[1][2] = fmaf(a1, bA.z, acc[1][2]); acc[1][3] = fmaf(a1, bA.w, acc[1][3]);
        acc[1][4] = fmaf(a1, bB.x, acc[1][4]); acc[1][5] = fmaf(a1, bB.y, acc[1][5]);
        acc[1][6] = fmaf(a1, bB.z, acc[1][6]); acc[1][7] = fmaf(a1, bB.w, acc[1][7]);
        acc[2][0] = fmaf(a2, bA.x, acc[2][0]); acc[2][1] = fmaf(a2, bA.y, acc[2][1]);
        acc[2][2] = fmaf(a2, bA.z, acc[2][2]); acc[2][3] = fmaf(a2, bA.w, acc[2][3]);
        acc[2][4] = fmaf(a2, bB.x, acc[2][4]); acc[2][5] = fmaf(a2, bB.y, acc[2][5]);
        acc[2][6] = fmaf(a2, bB.z, acc[2][6]); acc[2][7] = fmaf(a2, bB.w, acc[2][7]);
        acc[3][0] = fmaf(a3, bA.x, acc[3][0]); acc[3][1] = fmaf(a3, bA.y, acc[3][1]);
        acc[3][2] = fmaf(a3, bA.z, acc[3][2]); acc[3][3] = fmaf(a3, bA.w, acc[3][3]);
        acc[3][4] = fmaf(a3, bB.x, acc[3][4]); acc[3][5] = fmaf(a3, bB.y, acc[3][5]);
        acc[3][6] = fmaf(a3, bB.z, acc[3][6]); acc[3][7] = fmaf(a3, bB.w, acc[3][7]);
      }
      __syncthreads();
    }
  }

  float4 c0 = *(const float4*)&b1[tx * 4];
  float4 c1 = *(const float4*)&b1[64 + tx * 4];
  if constexpr (TWO) {
    float4 d0 = *(const float4*)&b2[tx * 4];
    float4 d1 = *(const float4*)&b2[64 + tx * 4];
    c0.x += d0.x; c0.y += d0.y; c0.z += d0.z; c0.w += d0.w;
    c1.x += d1.x; c1.y += d1.y; c1.z += d1.z; c1.w += d1.w;
  }
#pragma unroll
  for (int i = 0; i < 4; ++i) {
    int gr = r0 + ty * 4 + i;
    if (gr < nrows) {
      float4 o0, o1;
      o0.x = fmaxf(acc[i][0] + c0.x, 0.f);
      o0.y = fmaxf(acc[i][1] + c0.y, 0.f);
      o0.z = fmaxf(acc[i][2] + c0.z, 0.f);
      o0.w = fmaxf(acc[i][3] + c0.w, 0.f);
      o1.x = fmaxf(acc[i][4] + c1.x, 0.f);
      o1.y = fmaxf(acc[i][5] + c1.y, 0.f);
      o1.z = fmaxf(acc[i][6] + c1.z, 0.f);
      o1.w = fmaxf(acc[i][7] + c1.w, 0.f);
      *(float4*)(out + (size_t)gr * D + tx * 4) = o0;
      *(float4*)(out + (size_t)gr * D + 64 + tx * 4) = o1;
    }
  }
}

// ---------------- per-graph mean pooling (sorted gid -> segment partials) ----------------
#define PCHUNK 256
__global__ __launch_bounds__(128) void k_pool(const float* __restrict__ H,
                                              const int* __restrict__ gid,
                                              float* __restrict__ sums,
                                              float* __restrict__ cnt, int n) {
  int col = threadIdx.x;
  int start = blockIdx.x * PCHUNK;
  if (start >= n) return;
  int end = min(start + PCHUNK, n);
  float acc = 0.f;
  int cur = gid[start];
  int seglen = 0;
  for (int r = start; r < end; ++r) {
    int g = gid[r];
    if (g != cur) {
      atomicAdd(&sums[cur * D + col], acc);
      if (col == 0) atomicAdd(&cnt[cur], (float)seglen);
      acc = 0.f; seglen = 0; cur = g;
    }
    acc += H[(size_t)r * D + col];
    seglen++;
  }
  atomicAdd(&sums[cur * D + col], acc);
  if (col == 0) atomicAdd(&cnt[cur], (float)seglen);
}

// ---------------- final MLP on [16,128] ----------------
__global__ __launch_bounds__(256) void k_final(const float* __restrict__ sums,
                                               const float* __restrict__ cnt,
                                               const float* __restrict__ Wm1,
                                               const float* __restrict__ bm1,
                                               const float* __restrict__ Wm2,
                                               const float* __restrict__ bm2,
                                               float* __restrict__ out) {
  __shared__ float hg[16][128];
  __shared__ float t1[16][128];
  int tid = threadIdx.x;
  for (int i = tid; i < 16 * 128; i += 256) {
    int g = i >> 7, c = i & 127;
    hg[g][c] = sums[i] / fmaxf(cnt[g], 1.f);
  }
  __syncthreads();
  for (int i = tid; i < 16 * 128; i += 256) {
    int g = i >> 7, c = i & 127;
    float a = bm1[c];
    for (int k = 0; k < 128; ++k) a = fmaf(hg[g][k], Wm1[k * 128 + c], a);
    t1[g][c] = fmaxf(a, 0.f);
  }
  __syncthreads();
  int g = tid >> 4, l = tid & 15;
  float p = 0.f;
  for (int c = l; c < 128; c += 16) p = fmaf(t1[g][c], Wm2[c], p);
#pragma unroll
  for (int o = 8; o; o >>= 1) p += __shfl_down(p, o, 16);
  if (l == 0) out[g] = p + bm2[0];
}

extern "C" void kernel_launch(void* const* d_in, const int* in_sizes, int n_in,
                              void* d_out, int out_size, void* d_ws, size_t ws_size,
                              hipStream_t stream) {
  const float* x_tile = (const float*)d_in[0];
  const float* x_rr   = (const float*)d_in[1];
  const int* tt_src = (const int*)d_in[2];
  const int* tt_dst = (const int*)d_in[3];
  const int* rt_src = (const int*)d_in[4];
  const int* rt_dst = (const int*)d_in[5];
  const int* tr_src = (const int*)d_in[6];
  const int* tr_dst = (const int*)d_in[7];
  const int* tile_gid = (const int*)d_in[8];
  const float* W1_tt = (const float*)d_in[9];  const float* b1_tt = (const float*)d_in[10];
  const float* W1_rt = (const float*)d_in[11]; const float* b1_rt = (const float*)d_in[12];
  const float* W1_tr = (const float*)d_in[13]; const float* b1_tr = (const float*)d_in[14];
  const float* W2_tt = (const float*)d_in[15]; const float* b2_tt = (const float*)d_in[16];
  const float* W2_rt = (const float*)d_in[17]; const float* b2_rt = (const float*)d_in[18];
  const float* Wm1 = (const float*)d_in[21]; const float* bm1 = (const float*)d_in[22];
  const float* Wm2 = (const float*)d_in[23]; const float* bm2 = (const float*)d_in[24];

  char* ws = (char*)d_ws;
  size_t off = 0;
  auto alloc = [&](size_t elems) {
    void* p = ws + off;
    off += (elems * 4 + 255) & ~(size_t)255;
    return p;
  };
  // ---- zero region (memset each call) ----
  float* psum = (float*)alloc(N_G * D);
  float* pcnt = (float*)alloc(N_G);
  size_t zero_bytes = off;
  // ---- rest (all fully written before read) ----
  int* partial = (int*)alloc((size_t)6 * NCHK * N_TILE);
  int* rank = (int*)alloc(E_ALL);
  int* ideg_tt = (int*)alloc(N_TILE);
  int* ideg_rt = (int*)alloc(N_TILE);
  int* ideg_tr = (int*)alloc(N_RR);
  int* pp_tt = (int*)alloc(N_TILE);
  int* pp_rt = (int*)alloc(N_TILE);
  int* pp_tr = (int*)alloc(N_RR);
  int* bsum = (int*)alloc(3 * NB);
  int* bs = (int*)alloc(3 * (NB + 1));
  int* rp_tt = (int*)alloc(N_TILE + 1);
  int* rp_rt = (int*)alloc(N_TILE + 1);
  int* rp_tr = (int*)alloc(N_RR + 1);
  int2* pr_tt = (int2*)alloc((size_t)E_TT * 2);
  int2* pr_rt = (int2*)alloc((size_t)E_RT * 2);
  int2* pr_tr = (int2*)alloc((size_t)E_TR * 2);
  float* osc_tt = (float*)alloc(N_TILE);
  float* osc_rt = (float*)alloc(N_RR);
  float* osc_tr = (float*)alloc(N_TILE);
  float* isc_tt = (float*)alloc(N_TILE);
  float* isc_rt = (float*)alloc(N_TILE);
  float* isc_tr = (float*)alloc(N_RR);
  float* Abuf = (float*)alloc((size_t)N_TILE * D);
  float* Bbuf = (float*)alloc((size_t)N_TILE * D);
  float* Htile = (float*)alloc((size_t)N_TILE * D);
  float* Hrr = (float*)alloc((size_t)N_RR * D);
  (void)ws_size; (void)in_sizes; (void)n_in; (void)out_size;

  hipMemsetAsync(d_ws, 0, zero_bytes, stream);

  // ---- CSR build: zero global atomics, atomic-free fill via hist-rank ----
  k_hist<<<6 * NBKT * NCHK, 256, 0, stream>>>(
      tt_src, tt_dst, rt_src, rt_dst, tr_src, tr_dst, partial, rank);
  k_hreduce<<<(6 * N_TILE + 255) / 256, 256, 0, stream>>>(
      partial, ideg_tt, ideg_rt, ideg_tr, osc_tt, osc_rt, osc_tr);
  k_scan1<<<3 * NB, 1024, 0, stream>>>(ideg_tt, ideg_rt, ideg_tr, pp_tt, pp_rt, pp_tr, bsum);
  k_scan2<<<1, 256, 0, stream>>>(bsum, bs);
  k_finalize<<<(N_TILE + 255) / 256, 256, 0, stream>>>(
      pp_tt, pp_rt, pp_tr, bs, rp_tt, rp_rt, rp_tr,
      ideg_tt, ideg_rt, ideg_tr, isc_tt, isc_rt, isc_tr);
  k_fill<<<(E_ALL + 255) / 256, 256, 0, stream>>>(
      tt_src, tt_dst, rt_src, rt_dst, tr_src, tr_dst,
      rp_tt, rp_rt, rp_tr, osc_tt, osc_rt, osc_tr,
      partial, rank, pr_tt, pr_rt, pr_tr);

  const int gemmBlocks = (N_TILE + GBM - 1) / GBM;

  // ---- layer 1: all three aggs fused (tr output parked in Htile) ----
  {
    int totw = N_TILE + N_TILE + N_RR;
    k_agg3<<<(totw * 64 + 255) / 256, 256, 0, stream>>>(
        x_tile, rp_tt, pr_tt, isc_tt, Abuf, N_TILE,
        x_rr,  rp_rt, pr_rt, isc_rt, Bbuf, N_TILE,
        x_tile, rp_tr, pr_tr, isc_tr, Htile, N_RR);
  }
  // tr GEMM first (consumes Htile before it is overwritten)
  k_gemm<false><<<gemmBlocks, 256, 0, stream>>>(Htile, nullptr, W1_tr, nullptr, b1_tr, nullptr, Hrr, N_RR);
  k_gemm<true><<<gemmBlocks, 256, 0, stream>>>(Abuf, Bbuf, W1_tt, W1_rt, b1_tt, b1_rt, Htile, N_TILE);

  // ---- layer 2 (h2_rr never consumed -> tr relation skipped) ----
  {
    int totw = N_TILE + N_TILE;
    k_agg3<<<(totw * 64 + 255) / 256, 256, 0, stream>>>(
        Htile, rp_tt, pr_tt, isc_tt, Abuf, N_TILE,
        Hrr,   rp_rt, pr_rt, isc_rt, Bbuf, N_TILE,
        nullptr, nullptr, nullptr, nullptr, nullptr, 0);
  }
  k_gemm<true><<<gemmBlocks, 256, 0, stream>>>(Abuf, Bbuf, W2_tt, W2_rt, b2_tt, b2_rt, Htile, N_TILE);

  // ---- pooling + MLP head ----
  k_pool<<<(N_TILE + PCHUNK - 1) / PCHUNK, 128, 0, stream>>>(Htile, tile_gid, psum, pcnt, N_TILE);
  k_final<<<1, 256, 0, stream>>>(psum, pcnt, Wm1, bm1, Wm2, bm2, (float*)d_out);
}

// Round 9
// 457.325 us; speedup vs baseline: 1.3615x; 1.1659x over previous
//
#include <hip/hip_runtime.h>

#define N_TILE 50000
#define N_RR   50000
#define D      128
#define E_TT   800000
#define E_RT   400000
#define E_TR   400000
#define N_G    16
#define NB     ((N_TILE + 1023) / 1024)   // scan blocks per array (=49)
#define E_ALL  (E_TT + E_RT + E_TR)
#define BKT    8192                        // histogram bucket (bins per block), 32KB LDS
#define NBKT   ((N_TILE + BKT - 1) / BKT)  // =7
#define NCHK   25                          // edge chunks (all E divisible by 25)

static_assert(NB <= 64, "scan2 uses one wave per array");
static_assert(N_TILE == N_RR, "shared bucket geometry assumes equal node counts");
static_assert((BKT & (BKT - 1)) == 0, "bucket must be pow2");
static_assert(E_TT % NCHK == 0 && E_RT % NCHK == 0 && E_TR % NCHK == 0, "chunking");

typedef __attribute__((ext_vector_type(8))) short bf16x8;
typedef __attribute__((ext_vector_type(4))) float f32x4;
typedef unsigned short u16;

__device__ inline u16 f2bf(float f) {
  unsigned u = __float_as_uint(f);
  unsigned r = (u + 0x7FFFu + ((u >> 16) & 1u)) >> 16;   // RNE
  return (u16)r;
}
__device__ inline float bf2f(u16 h) { return __uint_as_float(((unsigned)h) << 16); }

// ---------------- bucketed LDS histogram + rank capture: NO global atomics ----
__global__ __launch_bounds__(256) void k_hist(
    const int* __restrict__ tt_src, const int* __restrict__ tt_dst,
    const int* __restrict__ rt_src, const int* __restrict__ rt_dst,
    const int* __restrict__ tr_src, const int* __restrict__ tr_dst,
    int* __restrict__ partial, int* __restrict__ rank) {
  __shared__ int h[BKT];
  int bid = blockIdx.x;
  int s = bid / (NBKT * NCHK);
  int rem = bid % (NBKT * NCHK);
  int b = rem / NCHK;
  int c = rem % NCHK;
  const int* arr; int E; int roff = 0;
  switch (s) {
    case 0: arr = tt_dst; E = E_TT; roff = 0; break;
    case 1: arr = rt_dst; E = E_RT; roff = E_TT; break;
    case 2: arr = tr_dst; E = E_TR; roff = E_TT + E_RT; break;
    case 3: arr = tt_src; E = E_TT; break;
    case 4: arr = rt_src; E = E_RT; break;
    default: arr = tr_src; E = E_TR; break;
  }
  bool isdst = s < 3;
  for (int j = threadIdx.x; j < BKT; j += 256) h[j] = 0;
  __syncthreads();
  int ec = E / NCHK;
  int lo = c * ec, hi = lo + ec;
  int base = b * BKT;
  for (int i = lo + threadIdx.x; i < hi; i += 256) {
    unsigned int off = (unsigned int)(arr[i] - base);
    if (off < BKT) {
      int r = atomicAdd(&h[off], 1);
      if (isdst) rank[roff + i] = r;
    }
  }
  __syncthreads();
  int* dst = partial + (size_t)(s * NCHK + c) * N_TILE;
  for (int j = threadIdx.x; j < BKT; j += 256) {
    int bin = base + j;
    if (bin < N_TILE) dst[bin] = h[j];
  }
}

// ---------------- reduce partials ----------------
__global__ __launch_bounds__(256) void k_hreduce(
    int* __restrict__ partial,
    int* __restrict__ id_tt, int* __restrict__ id_rt, int* __restrict__ id_tr,
    float* __restrict__ os_tt, float* __restrict__ os_rt, float* __restrict__ os_tr) {
  int t = blockIdx.x * 256 + threadIdx.x;
  if (t >= 6 * N_TILE) return;
  int s = t / N_TILE;
  int i = t - s * N_TILE;
  int* p = partial + (size_t)s * NCHK * N_TILE + i;
  int run = 0;
  if (s < 3) {
#pragma unroll
    for (int c = 0; c < NCHK; ++c) {
      int v = p[(size_t)c * N_TILE];
      p[(size_t)c * N_TILE] = run;
      run += v;
    }
    if (s == 0) id_tt[i] = run;
    else if (s == 1) id_rt[i] = run;
    else id_tr[i] = run;
  } else {
#pragma unroll
    for (int c = 0; c < NCHK; ++c) run += p[(size_t)c * N_TILE];
    float v = rsqrtf((float)max(run, 1));
    if (s == 3) os_tt[i] = v;
    else if (s == 4) os_rt[i] = v;
    else os_tr[i] = v;
  }
}

// ---------------- scan stage 1 ----------------
__global__ __launch_bounds__(1024) void k_scan1(const int* __restrict__ d0,
                                                const int* __restrict__ d1,
                                                const int* __restrict__ d2,
                                                int* __restrict__ p0,
                                                int* __restrict__ p1,
                                                int* __restrict__ p2,
                                                int* __restrict__ bsum) {
  int arr = blockIdx.x / NB;
  int blk = blockIdx.x % NB;
  const int* deg = arr == 0 ? d0 : (arr == 1 ? d1 : d2);
  int* part = arr == 0 ? p0 : (arr == 1 ? p1 : p2);
  __shared__ int ts[1024];
  int tid = threadIdx.x;
  int i = blk * 1024 + tid;
  int v = (i < N_TILE) ? deg[i] : 0;
  ts[tid] = v;
  __syncthreads();
  for (int d = 1; d < 1024; d <<= 1) {
    int t = (tid >= d) ? ts[tid - d] : 0;
    __syncthreads();
    ts[tid] += t;
    __syncthreads();
  }
  if (i < N_TILE) part[i] = ts[tid] - v;
  if (tid == 1023) bsum[arr * NB + blk] = ts[1023];
}

// ---------------- scan stage 2 ----------------
__global__ __launch_bounds__(256) void k_scan2(const int* __restrict__ bsum,
                                               int* __restrict__ bs) {
  int wv = threadIdx.x >> 6;
  int lane = threadIdx.x & 63;
  if (wv >= 3) return;
  int v = (lane < NB) ? bsum[wv * NB + lane] : 0;
  int orig = v;
#pragma unroll
  for (int o = 1; o < 64; o <<= 1) {
    int t = __shfl_up(v, o);
    if (lane >= o) v += t;
  }
  if (lane < NB) bs[wv * (NB + 1) + lane] = v - orig;
  if (lane == NB - 1) bs[wv * (NB + 1) + NB] = v;
}

// ---------------- finalize ----------------
__global__ void k_finalize(const int* __restrict__ pp_tt, const int* __restrict__ pp_rt,
                           const int* __restrict__ pp_tr, const int* __restrict__ bs,
                           int* __restrict__ rp_tt, int* __restrict__ rp_rt,
                           int* __restrict__ rp_tr,
                           const int* __restrict__ id_tt, const int* __restrict__ id_rt,
                           const int* __restrict__ id_tr,
                           float* __restrict__ is_tt, float* __restrict__ is_rt,
                           float* __restrict__ is_tr) {
  int i = blockIdx.x * blockDim.x + threadIdx.x;
  if (i >= N_TILE) return;
  int b = i >> 10;
  rp_tt[i] = pp_tt[i] + bs[0 * (NB + 1) + b];
  rp_rt[i] = pp_rt[i] + bs[1 * (NB + 1) + b];
  rp_tr[i] = pp_tr[i] + bs[2 * (NB + 1) + b];
  if (i == 0) {
    rp_tt[N_TILE] = bs[0 * (NB + 1) + NB];
    rp_rt[N_TILE] = bs[1 * (NB + 1) + NB];
    rp_tr[N_RR] = bs[2 * (NB + 1) + NB];
  }
  is_tt[i] = rsqrtf((float)max(id_tt[i], 1));
  is_rt[i] = rsqrtf((float)max(id_rt[i], 1));
  is_tr[i] = rsqrtf((float)max(id_tr[i], 1));
}

// ---------------- CSR fill: one thread per edge, atomic-free ----------------
__global__ __launch_bounds__(256) void k_fill(
    const int* __restrict__ tt_src, const int* __restrict__ tt_dst,
    const int* __restrict__ rt_src, const int* __restrict__ rt_dst,
    const int* __restrict__ tr_src, const int* __restrict__ tr_dst,
    const int* __restrict__ rp_tt, const int* __restrict__ rp_rt,
    const int* __restrict__ rp_tr,
    const float* __restrict__ os_tt, const float* __restrict__ os_rt,
    const float* __restrict__ os_tr,
    const int* __restrict__ partial, const int* __restrict__ rank,
    int2* __restrict__ pr_tt, int2* __restrict__ pr_rt, int2* __restrict__ pr_tr) {
  int i = blockIdx.x * 256 + threadIdx.x;
  if (i >= E_ALL) return;
  const int* srcA; const int* dstA; const int* rp; const float* os; int2* pr;
  int j, s, ec;
  if (i < E_TT) {
    s = 0; j = i; ec = E_TT / NCHK;
    srcA = tt_src; dstA = tt_dst; rp = rp_tt; os = os_tt; pr = pr_tt;
  } else if (i < E_TT + E_RT) {
    s = 1; j = i - E_TT; ec = E_RT / NCHK;
    srcA = rt_src; dstA = rt_dst; rp = rp_rt; os = os_rt; pr = pr_rt;
  } else {
    s = 2; j = i - E_TT - E_RT; ec = E_TR / NCHK;
    srcA = tr_src; dstA = tr_dst; rp = rp_tr; os = os_tr; pr = pr_tr;
  }
  int d = dstA[j];
  int c = j / ec;
  int slot = rp[d] + partial[(size_t)(s * NCHK + c) * N_TILE + d] + rank[i];
  int sv = srcA[j];
  int2 v;
  v.x = sv;
  v.y = __float_as_int(os[sv]);
  pr[slot] = v;
}

// ---------------- fused aggregation -> split-bf16 planes ----------------
// out_{hi,lo}[d][:] = split( isc[d] * sum_e w_e * x[src_e] )
__global__ __launch_bounds__(256) void k_agg3(
    const float* __restrict__ x0, const int* __restrict__ rp0, const int2* __restrict__ pr0,
    const float* __restrict__ isc0, u16* __restrict__ oh0, u16* __restrict__ ol0, int n0,
    const float* __restrict__ x1, const int* __restrict__ rp1, const int2* __restrict__ pr1,
    const float* __restrict__ isc1, u16* __restrict__ oh1, u16* __restrict__ ol1, int n1,
    const float* __restrict__ x2, const int* __restrict__ rp2, const int2* __restrict__ pr2,
    const float* __restrict__ isc2, u16* __restrict__ oh2, u16* __restrict__ ol2, int n2) {
  int gw = (blockIdx.x * blockDim.x + threadIdx.x) >> 6;
  int lane = threadIdx.x & 63;
  int half = lane >> 5;
  int l5 = lane & 31;
  const float* x; const int* rp; const int2* pr; const float* isc;
  u16* oh; u16* ol; int wid;
  if (gw < n0) { x = x0; rp = rp0; pr = pr0; isc = isc0; oh = oh0; ol = ol0; wid = gw; }
  else if (gw < n0 + n1) { x = x1; rp = rp1; pr = pr1; isc = isc1; oh = oh1; ol = ol1; wid = gw - n0; }
  else if (gw < n0 + n1 + n2) { x = x2; rp = rp2; pr = pr2; isc = isc2; oh = oh2; ol = ol2; wid = gw - n0 - n1; }
  else return;
  int beg = rp[wid], end = rp[wid + 1];
  float4 a0 = make_float4(0.f, 0.f, 0.f, 0.f);
  float4 a1 = a0, a2 = a0, a3 = a0;
  const float4* xb = (const float4*)x + l5;
  for (int e = beg; e < end; e += 8) {
    int2 p0, p1, p2, p3;
    float w0, w1, w2, w3;
    {
      int i0 = e + 0 + half, i1 = e + 2 + half, i2 = e + 4 + half, i3 = e + 6 + half;
      int lim = end - 1;
      p0 = pr[min(i0, lim)];
      p1 = pr[min(i1, lim)];
      p2 = pr[min(i2, lim)];
      p3 = pr[min(i3, lim)];
      w0 = (i0 < end) ? __int_as_float(p0.y) : 0.f;
      w1 = (i1 < end) ? __int_as_float(p1.y) : 0.f;
      w2 = (i2 < end) ? __int_as_float(p2.y) : 0.f;
      w3 = (i3 < end) ? __int_as_float(p3.y) : 0.f;
    }
    float4 v0 = xb[(size_t)p0.x * 32];
    float4 v1 = xb[(size_t)p1.x * 32];
    float4 v2 = xb[(size_t)p2.x * 32];
    float4 v3 = xb[(size_t)p3.x * 32];
    a0.x = fmaf(v0.x, w0, a0.x); a0.y = fmaf(v0.y, w0, a0.y);
    a0.z = fmaf(v0.z, w0, a0.z); a0.w = fmaf(v0.w, w0, a0.w);
    a1.x = fmaf(v1.x, w1, a1.x); a1.y = fmaf(v1.y, w1, a1.y);
    a1.z = fmaf(v1.z, w1, a1.z); a1.w = fmaf(v1.w, w1, a1.w);
    a2.x = fmaf(v2.x, w2, a2.x); a2.y = fmaf(v2.y, w2, a2.y);
    a2.z = fmaf(v2.z, w2, a2.z); a2.w = fmaf(v2.w, w2, a2.w);
    a3.x = fmaf(v3.x, w3, a3.x); a3.y = fmaf(v3.y, w3, a3.y);
    a3.z = fmaf(v3.z, w3, a3.z); a3.w = fmaf(v3.w, w3, a3.w);
  }
  float4 s;
  s.x = (a0.x + a1.x) + (a2.x + a3.x);
  s.y = (a0.y + a1.y) + (a2.y + a3.y);
  s.z = (a0.z + a1.z) + (a2.z + a3.z);
  s.w = (a0.w + a1.w) + (a2.w + a3.w);
  s.x += __shfl_xor(s.x, 32);
  s.y += __shfl_xor(s.y, 32);
  s.z += __shfl_xor(s.z, 32);
  s.w += __shfl_xor(s.w, 32);
  if (half == 0) {
    float iv = isc[wid];
    float4 r;
    r.x = s.x * iv; r.y = s.y * iv; r.z = s.z * iv; r.w = s.w * iv;
    ushort4 hv, lv;
    hv.x = f2bf(r.x); lv.x = f2bf(r.x - bf2f(hv.x));
    hv.y = f2bf(r.y); lv.y = f2bf(r.y - bf2f(hv.y));
    hv.z = f2bf(r.z); lv.z = f2bf(r.z - bf2f(hv.z));
    hv.w = f2bf(r.w); lv.w = f2bf(r.w - bf2f(hv.w));
    *(ushort4*)(oh + (size_t)wid * D + l5 * 4) = hv;
    *(ushort4*)(ol + (size_t)wid * D + l5 * 4) = lv;
  }
}

// ---------------- weight prep: split fp32 W[k][n] -> bf16 Wt{hi,lo}[n][k] ----------------
__global__ __launch_bounds__(256) void k_wprep(
    const float* __restrict__ W0, const float* __restrict__ W1,
    const float* __restrict__ W2, const float* __restrict__ W3,
    const float* __restrict__ W4,
    u16* __restrict__ T0h, u16* __restrict__ T0l,
    u16* __restrict__ T1h, u16* __restrict__ T1l,
    u16* __restrict__ T2h, u16* __restrict__ T2l,
    u16* __restrict__ T3h, u16* __restrict__ T3l,
    u16* __restrict__ T4h, u16* __restrict__ T4l) {
  int bid = blockIdx.x;
  int s = bid >> 6;                      // 64 blocks per weight
  int idx = ((bid & 63) << 8) + threadIdx.x;   // 0..16383 = n*128+k
  const float* W = s == 0 ? W0 : (s == 1 ? W1 : (s == 2 ? W2 : (s == 3 ? W3 : W4)));
  u16* Th = s == 0 ? T0h : (s == 1 ? T1h : (s == 2 ? T2h : (s == 3 ? T3h : T4h)));
  u16* Tl = s == 0 ? T0l : (s == 1 ? T1l : (s == 2 ? T2l : (s == 3 ? T3l : T4l)));
  int n = idx >> 7, k = idx & 127;
  float w = W[k * 128 + n];
  u16 h = f2bf(w);
  Th[idx] = h;
  Tl[idx] = f2bf(w - bf2f(h));
}

// ---------------- MFMA split-bf16 GEMM(+GEMM) + bias + relu ----------------
// out = relu( A1@W1 (+ A2@W2) + b1 (+ b2) ), A in split-bf16 planes, Wt=[n][k] planes.
// C = Ahi@Whi + Ahi@Wlo + Alo@Whi (3-product split reconstruction).
template<int NREL>
__global__ __launch_bounds__(256) void k_gemm_m(
    const u16* __restrict__ A1h, const u16* __restrict__ A1l,
    const u16* __restrict__ A2h, const u16* __restrict__ A2l,
    const u16* __restrict__ Wt1h, const u16* __restrict__ Wt1l,
    const u16* __restrict__ Wt2h, const u16* __restrict__ Wt2l,
    const float* __restrict__ b1, const float* __restrict__ b2,
    float* __restrict__ out, int nrows) {
  __shared__ u16 Ah[128][40];   // pad 40: 2-way-only LDS conflicts on b128 reads
  __shared__ u16 Al[128][40];
  __shared__ u16 Wh[128][40];   // [n][k]
  __shared__ u16 Wl[128][40];
  int tid = threadIdx.x;
  int wv = tid >> 6, lane = tid & 63;
  int l15 = lane & 15, lg = lane >> 4;
  int r0 = blockIdx.x * 128;
  f32x4 acc[2][8];
#pragma unroll
  for (int i = 0; i < 2; ++i)
#pragma unroll
    for (int j = 0; j < 8; ++j) acc[i][j] = (f32x4){0.f, 0.f, 0.f, 0.f};

  int srow = tid >> 1;             // 0..127
  int c0 = (tid & 1) * 16;         // u16 col base 0 or 16; each thread writes cols c0..c0+15
  int gr = r0 + srow;

  for (int rel = 0; rel < NREL; ++rel) {
    const u16* pAh = (NREL == 2 && rel) ? A2h : A1h;
    const u16* pAl = (NREL == 2 && rel) ? A2l : A1l;
    const u16* pWh = (NREL == 2 && rel) ? Wt2h : Wt1h;
    const u16* pWl = (NREL == 2 && rel) ? Wt2l : Wt1l;
    for (int k0 = 0; k0 < 128; k0 += 32) {
      __syncthreads();
      uint4 z = {0, 0, 0, 0};
      uint4 va0 = z, va1 = z, vb0 = z, vb1 = z;
      if (gr < nrows) {
        va0 = *(const uint4*)(pAh + (size_t)gr * 128 + k0 + c0);
        va1 = *(const uint4*)(pAh + (size_t)gr * 128 + k0 + c0 + 8);
        vb0 = *(const uint4*)(pAl + (size_t)gr * 128 + k0 + c0);
        vb1 = *(const uint4*)(pAl + (size_t)gr * 128 + k0 + c0 + 8);
      }
      *(uint4*)&Ah[srow][c0] = va0;
      *(uint4*)&Ah[srow][c0 + 8] = va1;
      *(uint4*)&Al[srow][c0] = vb0;
      *(uint4*)&Al[srow][c0 + 8] = vb1;
      *(uint4*)&Wh[srow][c0]     = *(const uint4*)(pWh + (size_t)srow * 128 + k0 + c0);
      *(uint4*)&Wh[srow][c0 + 8] = *(const uint4*)(pWh + (size_t)srow * 128 + k0 + c0 + 8);
      *(uint4*)&Wl[srow][c0]     = *(const uint4*)(pWl + (size_t)srow * 128 + k0 + c0);
      *(uint4*)&Wl[srow][c0 + 8] = *(const uint4*)(pWl + (size_t)srow * 128 + k0 + c0 + 8);
      __syncthreads();
      bf16x8 a0h = *(const bf16x8*)&Ah[wv * 32 + l15][lg * 8];
      bf16x8 a0l = *(const bf16x8*)&Al[wv * 32 + l15][lg * 8];
      bf16x8 a1h = *(const bf16x8*)&Ah[wv * 32 + 16 + l15][lg * 8];
      bf16x8 a1l = *(const bf16x8*)&Al[wv * 32 + 16 + l15][lg * 8];
#pragma unroll
      for (int ct = 0; ct < 8; ++ct) {
        bf16x8 bh = *(const bf16x8*)&Wh[ct * 16 + l15][lg * 8];
        bf16x8 bl = *(const bf16x8*)&Wl[ct * 16 + l15][lg * 8];
        acc[0][ct] = __builtin_amdgcn_mfma_f32_16x16x32_bf16(a0h, bh, acc[0][ct], 0, 0, 0);
        acc[0][ct] = __builtin_amdgcn_mfma_f32_16x16x32_bf16(a0h, bl, acc[0][ct], 0, 0, 0);
        acc[0][ct] = __builtin_amdgcn_mfma_f32_16x16x32_bf16(a0l, bh, acc[0][ct], 0, 0, 0);
        acc[1][ct] = __builtin_amdgcn_mfma_f32_16x16x32_bf16(a1h, bh, acc[1][ct], 0, 0, 0);
        acc[1][ct] = __builtin_amdgcn_mfma_f32_16x16x32_bf16(a1h, bl, acc[1][ct], 0, 0, 0);
        acc[1][ct] = __builtin_amdgcn_mfma_f32_16x16x32_bf16(a1l, bh, acc[1][ct], 0, 0, 0);
      }
    }
  }
  // epilogue: bias + relu; C layout col=lane&15, row=(lane>>4)*4+reg
#pragma unroll
  for (int ct = 0; ct < 8; ++ct) {
    int col = ct * 16 + l15;
    float bias = b1[col];
    if (NREL == 2) bias += b2[col];
#pragma unroll
    for (int rt = 0; rt < 2; ++rt) {
      int rowb = r0 + wv * 32 + rt * 16 + lg * 4;
#pragma unroll
      for (int r = 0; r < 4; ++r) {
        int row = rowb + r;
        if (row < nrows)
          out[(size_t)row * 128 + col] = fmaxf(acc[rt][ct][r] + bias, 0.f);
      }
    }
  }
}

// ---------------- per-graph mean pooling ----------------
#define PCHUNK 256
__global__ __launch_bounds__(128) void k_pool(const float* __restrict__ H,
                                              const int* __restrict__ gid,
                                              float* __restrict__ sums,
                                              float* __restrict__ cnt, int n) {
  int col = threadIdx.x;
  int start = blockIdx.x * PCHUNK;
  if (start >= n) return;
  int end = min(start + PCHUNK, n);
  float acc = 0.f;
  int cur = gid[start];
  int seglen = 0;
  for (int r = start; r < end; ++r) {
    int g = gid[r];
    if (g != cur) {
      atomicAdd(&sums[cur * D + col], acc);
      if (col == 0) atomicAdd(&cnt[cur], (float)seglen);
      acc = 0.f; seglen = 0; cur = g;
    }
    acc += H[(size_t)r * D + col];
    seglen++;
  }
  atomicAdd(&sums[cur * D + col], acc);
  if (col == 0) atomicAdd(&cnt[cur], (float)seglen);
}

// ---------------- final MLP on [16,128] ----------------
__global__ __launch_bounds__(256) void k_final(const float* __restrict__ sums,
                                               const float* __restrict__ cnt,
                                               const float* __restrict__ Wm1,
                                               const float* __restrict__ bm1,
                                               const float* __restrict__ Wm2,
                                               const float* __restrict__ bm2,
                                               float* __restrict__ out) {
  __shared__ float hg[16][128];
  __shared__ float t1[16][128];
  int tid = threadIdx.x;
  for (int i = tid; i < 16 * 128; i += 256) {
    int g = i >> 7, c = i & 127;
    hg[g][c] = sums[i] / fmaxf(cnt[g], 1.f);
  }
  __syncthreads();
  for (int i = tid; i < 16 * 128; i += 256) {
    int g = i >> 7, c = i & 127;
    float a = bm1[c];
    for (int k = 0; k < 128; ++k) a = fmaf(hg[g][k], Wm1[k * 128 + c], a);
    t1[g][c] = fmaxf(a, 0.f);
  }
  __syncthreads();
  int g = tid >> 4, l = tid & 15;
  float p = 0.f;
  for (int c = l; c < 128; c += 16) p = fmaf(t1[g][c], Wm2[c], p);
#pragma unroll
  for (int o = 8; o; o >>= 1) p += __shfl_down(p, o, 16);
  if (l == 0) out[g] = p + bm2[0];
}

extern "C" void kernel_launch(void* const* d_in, const int* in_sizes, int n_in,
                              void* d_out, int out_size, void* d_ws, size_t ws_size,
                              hipStream_t stream) {
  const float* x_tile = (const float*)d_in[0];
  const float* x_rr   = (const float*)d_in[1];
  const int* tt_src = (const int*)d_in[2];
  const int* tt_dst = (const int*)d_in[3];
  const int* rt_src = (const int*)d_in[4];
  const int* rt_dst = (const int*)d_in[5];
  const int* tr_src = (const int*)d_in[6];
  const int* tr_dst = (const int*)d_in[7];
  const int* tile_gid = (const int*)d_in[8];
  const float* W1_tt = (const float*)d_in[9];  const float* b1_tt = (const float*)d_in[10];
  const float* W1_rt = (const float*)d_in[11]; const float* b1_rt = (const float*)d_in[12];
  const float* W1_tr = (const float*)d_in[13]; const float* b1_tr = (const float*)d_in[14];
  const float* W2_tt = (const float*)d_in[15]; const float* b2_tt = (const float*)d_in[16];
  const float* W2_rt = (const float*)d_in[17]; const float* b2_rt = (const float*)d_in[18];
  const float* Wm1 = (const float*)d_in[21]; const float* bm1 = (const float*)d_in[22];
  const float* Wm2 = (const float*)d_in[23]; const float* bm2 = (const float*)d_in[24];

  char* ws = (char*)d_ws;
  size_t off = 0;
  auto allocB = [&](size_t bytes) {
    void* p = ws + off;
    off += (bytes + 255) & ~(size_t)255;
    return p;
  };
  // ---- zero region (memset each call) ----
  float* psum = (float*)allocB(N_G * D * 4);
  float* pcnt = (float*)allocB(N_G * 4);
  size_t zero_bytes = off;
  // ---- rest (all fully written before read) ----
  int* partial = (int*)allocB((size_t)6 * NCHK * N_TILE * 4);
  int* rank = (int*)allocB((size_t)E_ALL * 4);
  int* ideg_tt = (int*)allocB(N_TILE * 4);
  int* ideg_rt = (int*)allocB(N_TILE * 4);
  int* ideg_tr = (int*)allocB(N_RR * 4);
  int* pp_tt = (int*)allocB(N_TILE * 4);
  int* pp_rt = (int*)allocB(N_TILE * 4);
  int* pp_tr = (int*)allocB(N_RR * 4);
  int* bsum = (int*)allocB(3 * NB * 4);
  int* bs = (int*)allocB(3 * (NB + 1) * 4);
  int* rp_tt = (int*)allocB((N_TILE + 1) * 4);
  int* rp_rt = (int*)allocB((N_TILE + 1) * 4);
  int* rp_tr = (int*)allocB((N_RR + 1) * 4);
  int2* pr_tt = (int2*)allocB((size_t)E_TT * 8);
  int2* pr_rt = (int2*)allocB((size_t)E_RT * 8);
  int2* pr_tr = (int2*)allocB((size_t)E_TR * 8);
  float* osc_tt = (float*)allocB(N_TILE * 4);
  float* osc_rt = (float*)allocB(N_RR * 4);
  float* osc_tr = (float*)allocB(N_TILE * 4);
  float* isc_tt = (float*)allocB(N_TILE * 4);
  float* isc_rt = (float*)allocB(N_TILE * 4);
  float* isc_tr = (float*)allocB(N_RR * 4);
  u16* Ahi = (u16*)allocB((size_t)N_TILE * D * 2);
  u16* Alo = (u16*)allocB((size_t)N_TILE * D * 2);
  u16* Bhi = (u16*)allocB((size_t)N_TILE * D * 2);
  u16* Blo = (u16*)allocB((size_t)N_TILE * D * 2);
  u16* Chi = (u16*)allocB((size_t)N_RR * D * 2);
  u16* Clo = (u16*)allocB((size_t)N_RR * D * 2);
  float* Htile = (float*)allocB((size_t)N_TILE * D * 4);
  float* Hrr = (float*)allocB((size_t)N_RR * D * 4);
  u16* Wt1tt_h = (u16*)allocB(D * D * 2); u16* Wt1tt_l = (u16*)allocB(D * D * 2);
  u16* Wt1rt_h = (u16*)allocB(D * D * 2); u16* Wt1rt_l = (u16*)allocB(D * D * 2);
  u16* Wt1tr_h = (u16*)allocB(D * D * 2); u16* Wt1tr_l = (u16*)allocB(D * D * 2);
  u16* Wt2tt_h = (u16*)allocB(D * D * 2); u16* Wt2tt_l = (u16*)allocB(D * D * 2);
  u16* Wt2rt_h = (u16*)allocB(D * D * 2); u16* Wt2rt_l = (u16*)allocB(D * D * 2);
  (void)ws_size; (void)in_sizes; (void)n_in; (void)out_size;

  hipMemsetAsync(d_ws, 0, zero_bytes, stream);

  // ---- weight split (independent of CSR path) ----
  k_wprep<<<5 * 64, 256, 0, stream>>>(
      W1_tt, W1_rt, W1_tr, W2_tt, W2_rt,
      Wt1tt_h, Wt1tt_l, Wt1rt_h, Wt1rt_l, Wt1tr_h, Wt1tr_l,
      Wt2tt_h, Wt2tt_l, Wt2rt_h, Wt2rt_l);

  // ---- CSR build: zero global atomics, atomic-free fill via hist-rank ----
  k_hist<<<6 * NBKT * NCHK, 256, 0, stream>>>(
      tt_src, tt_dst, rt_src, rt_dst, tr_src, tr_dst, partial, rank);
  k_hreduce<<<(6 * N_TILE + 255) / 256, 256, 0, stream>>>(
      partial, ideg_tt, ideg_rt, ideg_tr, osc_tt, osc_rt, osc_tr);
  k_scan1<<<3 * NB, 1024, 0, stream>>>(ideg_tt, ideg_rt, ideg_tr, pp_tt, pp_rt, pp_tr, bsum);
  k_scan2<<<1, 256, 0, stream>>>(bsum, bs);
  k_finalize<<<(N_TILE + 255) / 256, 256, 0, stream>>>(
      pp_tt, pp_rt, pp_tr, bs, rp_tt, rp_rt, rp_tr,
      ideg_tt, ideg_rt, ideg_tr, isc_tt, isc_rt, isc_tr);
  k_fill<<<(E_ALL + 255) / 256, 256, 0, stream>>>(
      tt_src, tt_dst, rt_src, rt_dst, tr_src, tr_dst,
      rp_tt, rp_rt, rp_tr, osc_tt, osc_rt, osc_tr,
      partial, rank, pr_tt, pr_rt, pr_tr);

  const int gemmBlocks = (N_TILE + 127) / 128;

  // ---- layer 1: all three aggs fused, outputs split-bf16 planes ----
  {
    int totw = N_TILE + N_TILE + N_RR;
    k_agg3<<<(totw * 64 + 255) / 256, 256, 0, stream>>>(
        x_tile, rp_tt, pr_tt, isc_tt, Ahi, Alo, N_TILE,
        x_rr,  rp_rt, pr_rt, isc_rt, Bhi, Blo, N_TILE,
        x_tile, rp_tr, pr_tr, isc_tr, Chi, Clo, N_RR);
  }
  k_gemm_m<1><<<gemmBlocks, 256, 0, stream>>>(
      Chi, Clo, nullptr, nullptr, Wt1tr_h, Wt1tr_l, nullptr, nullptr,
      b1_tr, nullptr, Hrr, N_RR);
  k_gemm_m<2><<<gemmBlocks, 256, 0, stream>>>(
      Ahi, Alo, Bhi, Blo, Wt1tt_h, Wt1tt_l, Wt1rt_h, Wt1rt_l,
      b1_tt, b1_rt, Htile, N_TILE);

  // ---- layer 2 (h2_rr never consumed -> tr relation skipped) ----
  {
    int totw = N_TILE + N_TILE;
    k_agg3<<<(totw * 64 + 255) / 256, 256, 0, stream>>>(
        Htile, rp_tt, pr_tt, isc_tt, Ahi, Alo, N_TILE,
        Hrr,   rp_rt, pr_rt, isc_rt, Bhi, Blo, N_TILE,
        nullptr, nullptr, nullptr, nullptr, nullptr, nullptr, 0);
  }
  k_gemm_m<2><<<gemmBlocks, 256, 0, stream>>>(
      Ahi, Alo, Bhi, Blo, Wt2tt_h, Wt2tt_l, Wt2rt_h, Wt2rt_l,
      b2_tt, b2_rt, Htile, N_TILE);

  // ---- pooling + MLP head ----
  k_pool<<<(N_TILE + PCHUNK - 1) / PCHUNK, 128, 0, stream>>>(Htile, tile_gid, psum, pcnt, N_TILE);
  k_final<<<1, 256, 0, stream>>>(psum, pcnt, Wm1, bm1, Wm2, bm2, (float*)d_out);
}